// Round 1
// baseline (5676.820 us; speedup 1.0000x reference)
//
#include <hip/hip_runtime.h>
#include <stdint.h>

// LSTM(relu) persistent-kernel: B=64,S=1024,F=128,H=512.
// 4 batch-groups x 32 unit-wgs = 128 wgs, 64 threads (1 wave) each.
// Per wg: [U;W] slice (640 x 64 cols) lives in LDS (bf16) the whole run.
// Per step: z[16,64] = bias + x@W + h@U via mfma_f32_16x16x32_bf16,
// gates combined in-register (cols ordered i|f|g|o per 16-unit block),
// h exchanged via double-buffered global bf16 buffer + per-group counter barrier.

#define B_ 64
#define S_ 1024
#define F_ 128
#define H_ 512
#define G4_ 2048
#define BG_ 16          // batch rows per group
#define NWG 32          // wgs per group
#define LDK 648         // padded K stride (640+8) -> no 16-way LDS bank conflict
#define HBUF_ELEMS (B_ * H_)

typedef __attribute__((ext_vector_type(8))) short short8;  // 8 x bf16
typedef __attribute__((ext_vector_type(4))) float f32x4;

__device__ __forceinline__ unsigned short f2bf(float f) {
  union { float f; unsigned u; } v; v.f = f;
  unsigned u = v.u + 0x7fffu + ((v.u >> 16) & 1u);   // RNE
  return (unsigned short)(u >> 16);
}

__device__ __forceinline__ short8 pack2(f32x4 a, f32x4 b) {
  short8 r;
#pragma unroll
  for (int i = 0; i < 4; ++i) r[i] = (short)f2bf(a[i]);
#pragma unroll
  for (int i = 0; i < 4; ++i) r[4 + i] = (short)f2bf(b[i]);
  return r;
}

__global__ __launch_bounds__(64, 1) void lstm_pers(
    const float* __restrict__ x, const float* __restrict__ W,
    const float* __restrict__ U, const float* __restrict__ bias,
    float* __restrict__ out, unsigned int* ctr, unsigned short* hbuf) {

  __shared__ unsigned short V[64 * LDK];   // 82944 B; V[c][k], c = gate*16+unit

  const int tid  = threadIdx.x;            // 0..63 (one wave)
  const int l15  = tid & 15;
  const int koff = (tid >> 4) * 8;         // A/B frag k sub-offset

  const int blk   = blockIdx.x;            // 0..127
  const int grp   = blk & 3;               // batch group (0..3): same-XCD-ish spread
  const int j     = blk >> 2;              // unit block (0..31)
  const int ubase = j * 16;
  const int bbase = grp * BG_;
  unsigned int* myctr = ctr + grp * 32;    // 128 B apart per group

  // ---- one-time LDS fill: V[c][k] = bf16( k<512 ? U[k][gcol] : W[k-512][gcol] )
  // float4 loads: 64 cols per k row = 256 B contiguous global per k.
  for (int idx = tid; idx < (64 * 640) / 4; idx += 64) {
    int c4 = (idx & 15) * 4;               // col base 0..60, stays within one gate
    int k  = idx >> 4;                     // 0..639
    int gate = c4 >> 4, ui = c4 & 15;
    int gcol = gate * H_ + ubase + ui;
    f32x4 v4 = (k < H_)
      ? *(const f32x4*)(U + (size_t)k * G4_ + gcol)
      : *(const f32x4*)(W + (size_t)(k - H_) * G4_ + gcol);
#pragma unroll
    for (int q = 0; q < 4; ++q) V[(c4 + q) * LDK + k] = f2bf(v4[q]);
  }

  float bias_r[4];
#pragma unroll
  for (int g = 0; g < 4; ++g) bias_r[g] = bias[g * H_ + ubase + l15];

  __syncthreads();

  // per-lane pointers
  const float* xrow = x + (size_t)(bbase + l15) * (S_ * F_) + koff;
  const unsigned short* hrow0 = hbuf + (size_t)(bbase + l15) * H_ + koff;
  const unsigned short* vb[4];
#pragma unroll
  for (int tile = 0; tile < 4; ++tile) vb[tile] = V + (size_t)(tile * 16 + l15) * LDK;

  f32x4 cst = {0.f, 0.f, 0.f, 0.f};        // c-state: 4 (row,unit) pairs per lane
  const int drow = (tid >> 4) * 4;         // D-frag row base
  const int unit = ubase + l15;

  for (int t = 0; t < S_; ++t) {
    // ---- issue x loads first (independent of h; in flight during barrier poll)
    const float* xt = xrow + t * F_;
    f32x4 xq[8];
#pragma unroll
    for (int q = 0; q < 4; ++q) {
      xq[2 * q]     = *(const f32x4*)(xt + q * 32);
      xq[2 * q + 1] = *(const f32x4*)(xt + q * 32 + 4);
    }

    // ---- wait for h(t-1) from the 31 sibling wgs ----
    short8 af[16];
    if (t > 0) {
      if (tid == 0) {
        const unsigned target = (unsigned)(NWG * t);
        while (__hip_atomic_load(myctr, __ATOMIC_RELAXED, __HIP_MEMORY_SCOPE_AGENT) < target) {}
        (void)__hip_atomic_load(myctr, __ATOMIC_ACQUIRE, __HIP_MEMORY_SCOPE_AGENT);
      }
      __syncthreads();
      const unsigned short* hr = hrow0 + (size_t)(t & 1) * HBUF_ELEMS;
#pragma unroll
      for (int ks = 0; ks < 16; ++ks)          // issue all 16 A-frag loads (L2)
        af[ks] = *(const short8*)(hr + ks * 32);
    }

    // ---- acc = bias ----
    f32x4 acc[4];
#pragma unroll
    for (int tile = 0; tile < 4; ++tile) {
      f32x4 a; a[0] = a[1] = a[2] = a[3] = bias_r[tile];
      acc[tile] = a;
    }

    // ---- x @ W (k = 512..639): runs while h loads are in flight ----
#pragma unroll
    for (int q = 0; q < 4; ++q) {
      short8 a = pack2(xq[2 * q], xq[2 * q + 1]);
      const int kk = 512 + q * 32 + koff;
#pragma unroll
      for (int tile = 0; tile < 4; ++tile) {
        short8 b = *(const short8*)(vb[tile] + kk);
        acc[tile] = __builtin_amdgcn_mfma_f32_16x16x32_bf16(a, b, acc[tile], 0, 0, 0);
      }
    }

    // ---- h(t-1) @ U (k = 0..511) ----
    if (t > 0) {
#pragma unroll
      for (int ks = 0; ks < 16; ++ks) {
        const int kk = ks * 32 + koff;
#pragma unroll
        for (int tile = 0; tile < 4; ++tile) {
          short8 b = *(const short8*)(vb[tile] + kk);
          acc[tile] = __builtin_amdgcn_mfma_f32_16x16x32_bf16(af[ks], b, acc[tile], 0, 0, 0);
        }
      }
    }

    // ---- gates (same-lane: tile = gate), c/h update, stores ----
    unsigned short* hw = hbuf + (size_t)((t + 1) & 1) * HBUF_ELEMS;
#pragma unroll
    for (int r = 0; r < 4; ++r) {
      float zi = acc[0][r], zf = acc[1][r], zg = acc[2][r], zo = acc[3][r];
      float ig = 1.f / (1.f + __expf(-zi));
      float fg = 1.f / (1.f + __expf(-zf));
      float gg = fmaxf(zg, 0.f);                 // relu candidate
      float og = 1.f / (1.f + __expf(-zo));
      float cn = fg * cst[r] + ig * gg;
      cst[r] = cn;
      float h = og * fmaxf(cn, 0.f);             // relu output activation
      int grow = bbase + drow + r;
      hw[(size_t)grow * H_ + unit] = f2bf(h);
      out[((size_t)grow * S_ + t) * H_ + unit] = h;
    }

    __syncthreads();                              // drain stores (waitcnt) before arrive
    if (tid == 0)
      __hip_atomic_fetch_add(myctr, 1u, __ATOMIC_RELEASE, __HIP_MEMORY_SCOPE_AGENT);
  }
}

extern "C" void kernel_launch(void* const* d_in, const int* in_sizes, int n_in,
                              void* d_out, int out_size, void* d_ws, size_t ws_size,
                              hipStream_t stream) {
  const float* x = (const float*)d_in[0];
  const float* W = (const float*)d_in[1];
  const float* U = (const float*)d_in[2];
  const float* b = (const float*)d_in[3];
  float* out = (float*)d_out;

  unsigned int*   ctr  = (unsigned int*)d_ws;                       // 4 groups x 128 B
  unsigned short* hbuf = (unsigned short*)((char*)d_ws + 1024);     // 2 x 64 x 512 bf16

  hipMemsetAsync(d_ws, 0, 1024, stream);   // zero barrier counters each launch/replay

  lstm_pers<<<dim3(128), dim3(64), 0, stream>>>(x, W, U, b, out, ctr, hbuf);
}